// Round 8
// baseline (330.199 us; speedup 1.0000x reference)
//
#include <hip/hip_runtime.h>
#include <cstdint>

#define D 128
#define NBMAX 128      // max buckets (requires N <= 131072 for 17-bit rows)
#define BSH 10         // 1024 nodes per bucket
#define PASSA_TILE 4096
#define PASSA_VT 16
#define CAPB 32768     // pass-B LDS perm capacity (entries)

using short8 = __attribute__((ext_vector_type(8))) short;
using f32x4  = __attribute__((ext_vector_type(4))) float;
using half8  = __attribute__((ext_vector_type(8))) _Float16;

// fp32 -> bf16 bits, round-to-nearest-even
__device__ inline unsigned short f2bf(float f) {
    unsigned u = __float_as_uint(f);
    return (unsigned short)((u + 0x7FFFu + ((u >> 16) & 1u)) >> 16);
}
__device__ inline float bf2f(unsigned short h) {
    return __uint_as_float(((unsigned)h) << 16);
}

// ---------------- W prep: [Wrel | Wroot] -> fp16, row-major [128][256] ------
__global__ __launch_bounds__(256) void sage_wprep_h(
    const float* __restrict__ Wrel, const float* __restrict__ Wroot,
    _Float16* Wh)
{
    int t = blockIdx.x * 256 + threadIdx.x;   // 0..32767
    int j = t >> 8, k = t & 255;
    float f = (k < 128) ? Wrel[j * 128 + k] : Wroot[j * 128 + (k - 128)];
    Wh[t] = (_Float16)f;
}

// ---------------- x -> bf16 (for gather only) -------------------------------
__global__ __launch_bounds__(256) void sage_xprep(
    const float* __restrict__ x, unsigned short* xbf, long long total8)
{
    long long t = (long long)blockIdx.x * 256 + threadIdx.x;  // one per 8 elems
    if (t >= total8) return;
    const float4* src = reinterpret_cast<const float4*>(x) + t * 2;
    float4 f0 = src[0], f1 = src[1];
    short8 v;
    v[0] = (short)f2bf(f0.x); v[1] = (short)f2bf(f0.y);
    v[2] = (short)f2bf(f0.z); v[3] = (short)f2bf(f0.w);
    v[4] = (short)f2bf(f1.x); v[5] = (short)f2bf(f1.y);
    v[6] = (short)f2bf(f1.z); v[7] = (short)f2bf(f1.w);
    *reinterpret_cast<short8*>(xbf + t * 8) = v;
}

// ================= CSR build, LDS-staged two-level counting sort ============
__global__ __launch_bounds__(256) void bucket_hist(
    const int* __restrict__ col, int* gbh, int E, int nbuck)
{
    __shared__ int h[NBMAX];
    for (int i = threadIdx.x; i < NBMAX; i += 256) h[i] = 0;
    __syncthreads();
    int stride = gridDim.x * 256;
    for (int e = blockIdx.x * 256 + threadIdx.x; e < E; e += stride)
        atomicAdd(&h[col[e] >> BSH], 1);
    __syncthreads();
    for (int i = threadIdx.x; i < nbuck; i += 256)
        if (h[i]) atomicAdd(&gbh[i], h[i]);
}

__global__ __launch_bounds__(NBMAX) void bucket_scan(
    const int* __restrict__ gbh, int* boff, int* gcur, int nbuck)
{
    __shared__ int s[NBMAX];
    int t = threadIdx.x;
    int v = (t < nbuck) ? gbh[t] : 0;
    s[t] = v;
    __syncthreads();
    for (int off = 1; off < NBMAX; off <<= 1) {
        int u = (t >= off) ? s[t - off] : 0;
        __syncthreads();
        s[t] += u;
        __syncthreads();
    }
    if (t < nbuck) { int e = s[t] - v; boff[t] = e; gcur[t] = e; }
}

__global__ __launch_bounds__(256) void bucketize(
    const int* __restrict__ ei, int* gcur, unsigned* bucketed, int E, int nbuck)
{
    __shared__ int hcnt[NBMAX];
    __shared__ int hoff[NBMAX];
    __shared__ int cur[NBMAX];
    __shared__ int gbase[NBMAX];
    __shared__ unsigned staged[PASSA_TILE];

    int t = threadIdx.x;
    int base = blockIdx.x * PASSA_TILE;

    for (int i = t; i < NBMAX; i += 256) hcnt[i] = 0;
    __syncthreads();

    int myb[PASSA_VT];
    unsigned mypk[PASSA_VT];
    #pragma unroll
    for (int k = 0; k < PASSA_VT; ++k) {
        int e = base + k * 256 + t;
        if (e < E) {
            int c = ei[E + e];
            int r = ei[e];
            int b = c >> BSH;
            myb[k] = b;
            mypk[k] = ((unsigned)(c & ((1 << BSH) - 1)) << 17) | (unsigned)r;
            atomicAdd(&hcnt[b], 1);
        } else myb[k] = -1;
    }
    __syncthreads();

    if (t < NBMAX) hoff[t] = hcnt[t];
    __syncthreads();
    for (int off = 1; off < NBMAX; off <<= 1) {
        int u = 0;
        if (t < NBMAX && t >= off) u = hoff[t - off];
        __syncthreads();
        if (t < NBMAX) hoff[t] += u;
        __syncthreads();
    }
    if (t < NBMAX) cur[t] = hoff[t] - hcnt[t];
    __syncthreads();

    #pragma unroll
    for (int k = 0; k < PASSA_VT; ++k) {
        if (myb[k] >= 0) {
            int pos = atomicAdd(&cur[myb[k]], 1);
            staged[pos] = mypk[k];
        }
    }
    __syncthreads();

    if (t < nbuck && hcnt[t] > 0)
        gbase[t] = atomicAdd(&gcur[t], hcnt[t]);
    __syncthreads();

    if (t < nbuck) {
        int cnt = hcnt[t];
        int lo = cur[t] - cnt;
        int gb = gbase[t];
        for (int i = 0; i < cnt; ++i)
            bucketed[gb + i] = staged[lo + i];
    }
}

__global__ __launch_bounds__(256, 1) void bucket_csr(
    const unsigned* __restrict__ bucketed,
    const int* __restrict__ gbh, const int* __restrict__ boff,
    int* row_ptr, int* perm, int N, int E)
{
    __shared__ int lcur[1 << BSH];
    __shared__ int wtot[4];
    __shared__ int lperm_s[CAPB];

    int b = blockIdx.x;
    int t = threadIdx.x;
    int lane = t & 63, wv = t >> 6;
    int base = boff[b];
    int count = gbh[b];
    int node0 = b << BSH;
    int nnodes = min(1 << BSH, N - node0);

    for (int i = t; i < (1 << BSH); i += 256) lcur[i] = 0;
    __syncthreads();
    for (int i = t; i < count; i += 256)
        atomicAdd(&lcur[bucketed[base + i] >> 17], 1);
    __syncthreads();

    int loc[4];
    int run = 0;
    #pragma unroll
    for (int k = 0; k < 4; ++k) {
        int idx = t * 4 + k;
        loc[k] = run;
        run += (idx < nnodes) ? lcur[idx] : 0;
    }
    int incl = run;
    #pragma unroll
    for (int off = 1; off < 64; off <<= 1) {
        int u = __shfl_up(incl, off, 64);
        if (lane >= off) incl += u;
    }
    if (lane == 63) wtot[wv] = incl;
    __syncthreads();
    int woff = 0;
    for (int w = 0; w < wv; ++w) woff += wtot[w];
    int texcl = woff + (incl - run);
    __syncthreads();
    #pragma unroll
    for (int k = 0; k < 4; ++k) {
        int idx = t * 4 + k;
        if (idx < nnodes) {
            int ex = texcl + loc[k];
            row_ptr[node0 + idx] = base + ex;
            lcur[idx] = ex;
        }
    }
    if (t == 0 && node0 + nnodes == N) row_ptr[N] = base + count;
    __syncthreads();

    if (count <= CAPB) {
        for (int i = t; i < count; i += 256) {
            unsigned pk = bucketed[base + i];
            int pos = atomicAdd(&lcur[pk >> 17], 1);
            lperm_s[pos] = (int)(pk & 0x1FFFF);
        }
        __syncthreads();
        for (int i = t; i < count; i += 256)
            perm[base + i] = lperm_s[i];
    } else {
        for (int i = t; i < count; i += 256) {
            unsigned pk = bucketed[base + i];
            int pos = atomicAdd(&lcur[pk >> 17], 1);
            perm[base + pos] = (int)(pk & 0x1FFFF);
        }
    }
}

// ================= emergency old CSR path ==================================
__global__ __launch_bounds__(256) void sage_hist_old(
    const int* __restrict__ ei, int* hist, int E)
{
    int e = blockIdx.x * 256 + threadIdx.x;
    if (e < E) atomicAdd(&hist[ei[E + e]], 1);
}
__global__ __launch_bounds__(1024) void sage_scan_old(
    const int* __restrict__ hist, int* row_ptr, int* cursor, int N)
{
    __shared__ int s[1024];
    int t = threadIdx.x;
    int chunk = (N + 1023) / 1024;
    int lo = t * chunk, hi = min(lo + chunk, N);
    int sum = 0;
    for (int i = lo; i < hi; ++i) sum += hist[i];
    s[t] = sum;
    __syncthreads();
    for (int off = 1; off < 1024; off <<= 1) {
        int v = (t >= off) ? s[t - off] : 0;
        __syncthreads();
        s[t] += v;
        __syncthreads();
    }
    int p = s[t] - sum;
    for (int i = lo; i < hi; ++i) {
        row_ptr[i] = p; cursor[i] = p; p += hist[i];
    }
    if (t == 1023) row_ptr[N] = s[1023];
}
__global__ __launch_bounds__(256) void sage_fill_old(
    const int* __restrict__ ei, int* cursor, int* perm, int E)
{
    int e = blockIdx.x * 256 + threadIdx.x;
    if (e < E) {
        int p = atomicAdd(&cursor[ei[E + e]], 1);
        perm[p] = ei[e];
    }
}

// ============ fused gather + transform ======================================
// Block = 64 nodes, 4 waves, 16 nodes/wave.
// Phase 1: wave gathers bf16 x rows -> fp32 mean rows in LDS (XOR-swizzled).
// Phase 2: MFMA fp16: out = normalize([mean|x] @ [Wrel|Wroot]^T + b).
// Each wave reads only its own LDS rows -> no __syncthreads needed.
// LDS swizzle: float4 at (row, col4) lives at byte row*512 + ((col4*16) ^ ((row&7)<<4)).
__global__ __launch_bounds__(256) void sage_fused(
    const unsigned short* __restrict__ xbf,   // bf16 x (gather source)
    const float* __restrict__ xg,             // fp32 x (root term)
    const int* __restrict__ row_ptr,
    const int* __restrict__ perm,
    const _Float16* __restrict__ Wh,          // [128][256] fp16
    const float* __restrict__ brel,
    float* __restrict__ out, int N)
{
    __shared__ float a_lds[64 * D];           // 32 KiB

    const int tid  = threadIdx.x;
    const int wave = tid >> 6;
    const int lane = tid & 63;
    const int l15  = lane & 15;
    const int hi4  = lane >> 4;               // 0..3
    const int wbase = blockIdx.x * 64 + wave * 16;
    char* lds_c = reinterpret_cast<char*>(a_lds);

    // prefetch x fp32 root rows (k 128..255, kb 4..7); latency hides under phase 1
    const int mrow = min(wbase + l15, N - 1);
    const float* xrow = xg + (size_t)mrow * D;
    float4 xpf[8];
    #pragma unroll
    for (int q = 0; q < 4; ++q) {
        xpf[2 * q]     = *reinterpret_cast<const float4*>(xrow + q * 32 + hi4 * 8);
        xpf[2 * q + 1] = *reinterpret_cast<const float4*>(xrow + q * 32 + hi4 * 8 + 4);
    }

    // ---- phase 1: gather means for this wave's 16 nodes into LDS
    int rp = 0;
    if (lane < 17) rp = row_ptr[min(wbase + lane, N)];
    for (int i = 0; i < 16; ++i) {
        int node = wbase + i;
        int start = __shfl(rp, i, 64);
        int end   = __shfl(rp, i + 1, 64);
        float acc[8] = {0.f, 0.f, 0.f, 0.f, 0.f, 0.f, 0.f, 0.f};
        if (node < N) {
            for (int e = start + hi4; e < end; e += 4) {
                int r = perm[e];
                short8 v = *reinterpret_cast<const short8*>(xbf + (size_t)r * D + l15 * 8);
                #pragma unroll
                for (int el = 0; el < 8; ++el)
                    acc[el] += bf2f((unsigned short)v[el]);
            }
        }
        #pragma unroll
        for (int el = 0; el < 8; ++el) {
            acc[el] += __shfl_xor(acc[el], 16, 64);
            acc[el] += __shfl_xor(acc[el], 32, 64);
        }
        if (hi4 == 0) {
            float sc = (node < N) ? 1.0f / fmaxf((float)(end - start), 1.0f) : 0.0f;
            int row = wave * 16 + i;
            int swz = (row & 7) << 4;
            int byte0 = row * 512 + ((l15 * 32) ^ swz);
            int byte1 = row * 512 + ((l15 * 32 + 16) ^ swz);
            *reinterpret_cast<float4*>(lds_c + byte0) =
                make_float4(acc[0] * sc, acc[1] * sc, acc[2] * sc, acc[3] * sc);
            *reinterpret_cast<float4*>(lds_c + byte1) =
                make_float4(acc[4] * sc, acc[5] * sc, acc[6] * sc, acc[7] * sc);
        }
    }
    // (no barrier: wave reads only rows it wrote)

    // ---- phase 2: MFMA fp16
    f32x4 acc2[8];
    #pragma unroll
    for (int nt = 0; nt < 8; ++nt) acc2[nt] = (f32x4){0.f, 0.f, 0.f, 0.f};

    #pragma unroll
    for (int kb = 0; kb < 8; ++kb) {
        float fv[8];
        if (kb < 4) {
            int row = wave * 16 + l15;
            int swz = (row & 7) << 4;
            int col4 = kb * 8 + hi4 * 2;
            float4 f0 = *reinterpret_cast<const float4*>(lds_c + row * 512 + ((col4 * 16) ^ swz));
            float4 f1 = *reinterpret_cast<const float4*>(lds_c + row * 512 + (((col4 + 1) * 16) ^ swz));
            fv[0] = f0.x; fv[1] = f0.y; fv[2] = f0.z; fv[3] = f0.w;
            fv[4] = f1.x; fv[5] = f1.y; fv[6] = f1.z; fv[7] = f1.w;
        } else {
            float4 f0 = xpf[2 * (kb - 4)];
            float4 f1 = xpf[2 * (kb - 4) + 1];
            fv[0] = f0.x; fv[1] = f0.y; fv[2] = f0.z; fv[3] = f0.w;
            fv[4] = f1.x; fv[5] = f1.y; fv[6] = f1.z; fv[7] = f1.w;
        }
        half8 ah;
        #pragma unroll
        for (int el = 0; el < 8; ++el) ah[el] = (_Float16)fv[el];
        const int krow = kb * 32 + hi4 * 8;
        #pragma unroll
        for (int nt = 0; nt < 8; ++nt) {
            half8 bh = *reinterpret_cast<const half8*>(Wh + (size_t)(nt * 16 + l15) * 256 + krow);
            acc2[nt] = __builtin_amdgcn_mfma_f32_16x16x32_f16(ah, bh, acc2[nt], 0, 0, 0);
        }
    }

    float bias[8];
    #pragma unroll
    for (int nt = 0; nt < 8; ++nt) bias[nt] = brel[nt * 16 + l15];

    #pragma unroll
    for (int r = 0; r < 4; ++r) {
        float ss = 0.f;
        #pragma unroll
        for (int nt = 0; nt < 8; ++nt) {
            float a = acc2[nt][r] + bias[nt];
            acc2[nt][r] = a;
            ss = fmaf(a, a, ss);
        }
        ss += __shfl_xor(ss, 1, 64);
        ss += __shfl_xor(ss, 2, 64);
        ss += __shfl_xor(ss, 4, 64);
        ss += __shfl_xor(ss, 8, 64);
        float inv = 1.0f / fmaxf(sqrtf(ss), 1e-12f);
        int row = wbase + (lane >> 4) * 4 + r;
        if (row < N) {
            float* o = out + (size_t)row * D + l15;
            #pragma unroll
            for (int nt = 0; nt < 8; ++nt)
                o[nt * 16] = acc2[nt][r] * inv;
        }
    }
}

extern "C" void kernel_launch(void* const* d_in, const int* in_sizes, int n_in,
                              void* d_out, int out_size, void* d_ws, size_t ws_size,
                              hipStream_t stream)
{
    const float* x    = (const float*)d_in[0];
    const int*   ei   = (const int*)d_in[2];
    const float* Wrel = (const float*)d_in[3];
    const float* brel = (const float*)d_in[4];
    const float* Wroot= (const float*)d_in[5];
    int N = in_sizes[0] / D;
    int E = in_sizes[2] / 2;
    float* out = (float*)d_out;

    // ws layout: Wh[32768] (_Float16) | xbf[N*D] (ushort) |
    //   gbh[NBMAX] boff[NBMAX] gcur[NBMAX] row_ptr[N+1] bucketed[E] perm[E] (int)
    _Float16* Wh = (_Float16*)d_ws;
    unsigned short* xbf = (unsigned short*)(Wh + 32768);

    sage_wprep_h<<<128, 256, 0, stream>>>(Wrel, Wroot, Wh);
    long long total8 = (long long)N * D / 8;
    sage_xprep<<<(int)((total8 + 255) / 256), 256, 0, stream>>>(x, xbf, total8);

    int nbuck = (N + (1 << BSH) - 1) >> BSH;
    int* gbh     = (int*)(xbf + (size_t)N * D);
    int* boff    = gbh + NBMAX;
    int* gcur    = boff + NBMAX;
    int* row_ptr = gcur + NBMAX;
    unsigned* bucketed = (unsigned*)(row_ptr + N + 1);
    int* perm    = (int*)(bucketed + E);
    size_t need  = (size_t)((char*)(perm + E) - (char*)d_ws);

    if (N <= (1 << 17) && nbuck <= NBMAX && need <= ws_size) {
        hipMemsetAsync(gbh, 0, NBMAX * sizeof(int), stream);
        bucket_hist<<<256, 256, 0, stream>>>(ei + E, gbh, E, nbuck);
        bucket_scan<<<1, NBMAX, 0, stream>>>(gbh, boff, gcur, nbuck);
        bucketize<<<(E + PASSA_TILE - 1) / PASSA_TILE, 256, 0, stream>>>(
            ei, gcur, bucketed, E, nbuck);
        bucket_csr<<<nbuck, 256, 0, stream>>>(
            bucketed, gbh, boff, row_ptr, perm, N, E);
        sage_fused<<<(N + 63) / 64, 256, 0, stream>>>(
            xbf, x, row_ptr, perm, Wh, brel, out, N);
    } else {
        // emergency path: old hist/scan/fill CSR, then the same fused kernel
        int* hist    = (int*)(xbf + (size_t)N * D);
        int* rp      = hist + N;
        int* cursor  = rp + N + 1;
        int* perm2   = cursor + N;
        hipMemsetAsync(hist, 0, (size_t)N * sizeof(int), stream);
        int eblocks = (E + 255) / 256;
        sage_hist_old<<<eblocks, 256, 0, stream>>>(ei, hist, E);
        sage_scan_old<<<1, 1024, 0, stream>>>(hist, rp, cursor, N);
        sage_fill_old<<<eblocks, 256, 0, stream>>>(ei, cursor, perm2, E);
        sage_fused<<<(N + 63) / 64, 256, 0, stream>>>(
            xbf, x, rp, perm2, Wh, brel, out, N);
    }
}

// Round 9
// 306.578 us; speedup vs baseline: 1.0770x; 1.0770x over previous
//
#include <hip/hip_runtime.h>
#include <cstdint>

#define D 128
#define NBMAX 256      // max buckets
#define BSH 9          // 512 nodes per bucket
#define PASSA_TILE 4096
#define PASSA_VT 16

using short8 = __attribute__((ext_vector_type(8))) short;
using f32x4  = __attribute__((ext_vector_type(4))) float;
using half8  = __attribute__((ext_vector_type(8))) _Float16;

// ---------------- W prep: [Wrel | Wroot] -> fp16, row-major [128][256] ------
__global__ __launch_bounds__(256) void sage_wprep_h(
    const float* __restrict__ Wrel, const float* __restrict__ Wroot,
    _Float16* Wh)
{
    int t = blockIdx.x * 256 + threadIdx.x;   // 0..32767
    int j = t >> 8, k = t & 255;
    float f = (k < 128) ? Wrel[j * 128 + k] : Wroot[j * 128 + (k - 128)];
    Wh[t] = (_Float16)f;
}

// ---------------- x -> fp16 -------------------------------------------------
__global__ __launch_bounds__(256) void sage_xprep_h(
    const float* __restrict__ x, _Float16* xh, long long total8)
{
    long long t = (long long)blockIdx.x * 256 + threadIdx.x;  // one per 8 elems
    if (t >= total8) return;
    const float4* src = reinterpret_cast<const float4*>(x) + t * 2;
    float4 f0 = src[0], f1 = src[1];
    half8 v;
    v[0] = (_Float16)f0.x; v[1] = (_Float16)f0.y;
    v[2] = (_Float16)f0.z; v[3] = (_Float16)f0.w;
    v[4] = (_Float16)f1.x; v[5] = (_Float16)f1.y;
    v[6] = (_Float16)f1.z; v[7] = (_Float16)f1.w;
    *reinterpret_cast<half8*>(xh + t * 8) = v;
}

// ================= CSR build ================================================
__global__ __launch_bounds__(256) void bucket_hist(
    const int* __restrict__ col, int* gbh, int E, int nbuck)
{
    __shared__ int h[NBMAX];
    for (int i = threadIdx.x; i < NBMAX; i += 256) h[i] = 0;
    __syncthreads();
    int stride = gridDim.x * 256;
    for (int e = blockIdx.x * 256 + threadIdx.x; e < E; e += stride)
        atomicAdd(&h[col[e] >> BSH], 1);
    __syncthreads();
    for (int i = threadIdx.x; i < nbuck; i += 256)
        if (h[i]) atomicAdd(&gbh[i], h[i]);
}

__global__ __launch_bounds__(NBMAX) void bucket_scan(
    const int* __restrict__ gbh, int* boff, int* gcur, int nbuck)
{
    __shared__ int s[NBMAX];
    int t = threadIdx.x;
    int v = (t < nbuck) ? gbh[t] : 0;
    s[t] = v;
    __syncthreads();
    for (int off = 1; off < NBMAX; off <<= 1) {
        int u = (t >= off) ? s[t - off] : 0;
        __syncthreads();
        s[t] += u;
        __syncthreads();
    }
    if (t < nbuck) { int e = s[t] - v; boff[t] = e; gcur[t] = e; }
}

// bucketize: LDS-rank each 4096-edge tile, cooperative binary-search copy-out.
// Entry = (col_low << 17) | row  (4B); col_low 9 bits, row 17 bits.
__global__ __launch_bounds__(256) void bucketize(
    const int* __restrict__ ei, int* gcur, unsigned* bucketed, int E, int nbuck)
{
    __shared__ int hcnt[NBMAX];
    __shared__ int hoff[NBMAX];
    __shared__ int cur[NBMAX];
    __shared__ int sstart[NBMAX];
    __shared__ int gbase[NBMAX];
    __shared__ unsigned staged[PASSA_TILE];

    int t = threadIdx.x;
    int base = blockIdx.x * PASSA_TILE;
    int tile_cnt = min(PASSA_TILE, E - base);

    for (int i = t; i < NBMAX; i += 256) hcnt[i] = 0;
    __syncthreads();

    int myb[PASSA_VT];
    unsigned mypk[PASSA_VT];
    #pragma unroll
    for (int k = 0; k < PASSA_VT; ++k) {
        int e = base + k * 256 + t;
        if (e < E) {
            int c = ei[E + e];
            int r = ei[e];
            int b = c >> BSH;
            myb[k] = b;
            mypk[k] = ((unsigned)(c & ((1 << BSH) - 1)) << 17) | (unsigned)r;
            atomicAdd(&hcnt[b], 1);
        } else myb[k] = -1;
    }
    __syncthreads();

    hoff[t] = hcnt[t];                    // NBMAX == blockDim
    __syncthreads();
    for (int off = 1; off < NBMAX; off <<= 1) {
        int u = (t >= off) ? hoff[t - off] : 0;
        __syncthreads();
        hoff[t] += u;
        __syncthreads();
    }
    int st = hoff[t] - hcnt[t];
    cur[t] = st;
    sstart[t] = st;
    __syncthreads();

    #pragma unroll
    for (int k = 0; k < PASSA_VT; ++k) {
        if (myb[k] >= 0) {
            int pos = atomicAdd(&cur[myb[k]], 1);
            staged[pos] = mypk[k];
        }
    }
    __syncthreads();

    if (t < nbuck && hcnt[t] > 0)
        gbase[t] = atomicAdd(&gcur[t], hcnt[t]);
    __syncthreads();

    // cooperative copy-out: binary search owning bucket for each slot
    for (int i = t; i < tile_cnt; i += 256) {
        int lo = 0, hi = nbuck - 1;
        while (lo < hi) {
            int mid = (lo + hi + 1) >> 1;
            if (sstart[mid] <= i) lo = mid; else hi = mid - 1;
        }
        bucketed[gbase[lo] + (i - sstart[lo])] = staged[i];
    }
}

// per-bucket local CSR: 512-node hist+scan in LDS; perm written directly
// (scatter confined to a 32KB window -> L2-absorbed). LDS = 2KB.
__global__ __launch_bounds__(256) void bucket_csr(
    const unsigned* __restrict__ bucketed,
    const int* __restrict__ gbh, const int* __restrict__ boff,
    int* row_ptr, int* perm, int N, int E)
{
    __shared__ int lcur[1 << BSH];
    __shared__ int wtot[4];

    int b = blockIdx.x;
    int t = threadIdx.x;
    int lane = t & 63, wv = t >> 6;
    int base = boff[b];
    int count = gbh[b];
    int node0 = b << BSH;
    int nnodes = min(1 << BSH, N - node0);

    for (int i = t; i < (1 << BSH); i += 256) lcur[i] = 0;
    __syncthreads();
    for (int i = t; i < count; i += 256)
        atomicAdd(&lcur[bucketed[base + i] >> 17], 1);
    __syncthreads();

    int idx0 = t * 2, idx1 = t * 2 + 1;
    int v0 = (idx0 < nnodes) ? lcur[idx0] : 0;
    int v1 = (idx1 < nnodes) ? lcur[idx1] : 0;
    int tsum = v0 + v1;
    int incl = tsum;
    #pragma unroll
    for (int off = 1; off < 64; off <<= 1) {
        int u = __shfl_up(incl, off, 64);
        if (lane >= off) incl += u;
    }
    if (lane == 63) wtot[wv] = incl;
    __syncthreads();
    int woff = 0;
    for (int w = 0; w < wv; ++w) woff += wtot[w];
    int texcl = woff + (incl - tsum);
    __syncthreads();                     // all lcur reads done
    if (idx0 < nnodes) { row_ptr[node0 + idx0] = base + texcl;      lcur[idx0] = texcl; }
    if (idx1 < nnodes) { row_ptr[node0 + idx1] = base + texcl + v0; lcur[idx1] = texcl + v0; }
    if (t == 0 && node0 + nnodes == N) row_ptr[N] = base + count;
    __syncthreads();

    for (int i = t; i < count; i += 256) {
        unsigned pk = bucketed[base + i];
        int pos = atomicAdd(&lcur[pk >> 17], 1);
        perm[base + pos] = (int)(pk & 0x1FFFF);
    }
}

// ================= emergency old CSR path ==================================
__global__ __launch_bounds__(256) void sage_hist_old(
    const int* __restrict__ ei, int* hist, int E)
{
    int e = blockIdx.x * 256 + threadIdx.x;
    if (e < E) atomicAdd(&hist[ei[E + e]], 1);
}
__global__ __launch_bounds__(1024) void sage_scan_old(
    const int* __restrict__ hist, int* row_ptr, int* cursor, int N)
{
    __shared__ int s[1024];
    int t = threadIdx.x;
    int chunk = (N + 1023) / 1024;
    int lo = t * chunk, hi = min(lo + chunk, N);
    int sum = 0;
    for (int i = lo; i < hi; ++i) sum += hist[i];
    s[t] = sum;
    __syncthreads();
    for (int off = 1; off < 1024; off <<= 1) {
        int v = (t >= off) ? s[t - off] : 0;
        __syncthreads();
        s[t] += v;
        __syncthreads();
    }
    int p = s[t] - sum;
    for (int i = lo; i < hi; ++i) {
        row_ptr[i] = p; cursor[i] = p; p += hist[i];
    }
    if (t == 1023) row_ptr[N] = s[1023];
}
__global__ __launch_bounds__(256) void sage_fill_old(
    const int* __restrict__ ei, int* cursor, int* perm, int E)
{
    int e = blockIdx.x * 256 + threadIdx.x;
    if (e < E) {
        int p = atomicAdd(&cursor[ei[E + e]], 1);
        perm[p] = ei[e];
    }
}

// ---------------- gather (fp16 x): mean -> d_out (fp32) ---------------------
// one wave per node; 4 edges in parallel (16 lanes x half8 each)
__global__ __launch_bounds__(256) void sage_gather_h(
    const _Float16* __restrict__ xh,
    const int* __restrict__ row_ptr,
    const int* __restrict__ perm,
    float* out, int N)
{
    int wave = threadIdx.x >> 6;
    int lane = threadIdx.x & 63;
    int node = blockIdx.x * 4 + wave;
    if (node >= N) return;
    int start = row_ptr[node], end = row_ptr[node + 1];
    int g = lane >> 4, j = lane & 15;
    float acc[8] = {0.f, 0.f, 0.f, 0.f, 0.f, 0.f, 0.f, 0.f};
    for (int e = start + g; e < end; e += 4) {
        int r = perm[e];
        half8 v = *reinterpret_cast<const half8*>(xh + (size_t)r * D + j * 8);
        #pragma unroll
        for (int el = 0; el < 8; ++el)
            acc[el] += (float)v[el];
    }
    #pragma unroll
    for (int el = 0; el < 8; ++el) {
        acc[el] += __shfl_xor(acc[el], 16, 64);
        acc[el] += __shfl_xor(acc[el], 32, 64);
    }
    if (g == 0) {
        float sc = 1.0f / fmaxf((float)(end - start), 1.0f);
        float4* o = reinterpret_cast<float4*>(out + (size_t)node * D + j * 8);
        o[0] = make_float4(acc[0] * sc, acc[1] * sc, acc[2] * sc, acc[3] * sc);
        o[1] = make_float4(acc[4] * sc, acc[5] * sc, acc[6] * sc, acc[7] * sc);
    }
}

// ---------------- transform (fp16 MFMA, in-place on d_out) ------------------
// out = normalize([mean | x] @ [Wrel|Wroot]^T + b). A: mean fp32->fp16 (kb 0..3),
// x fp16 direct (kb 4..7). B: Wh fp16 direct. 16 rows/wave.
__global__ __launch_bounds__(256, 2) void sage_transform_h(
    float* inout,
    const _Float16* __restrict__ xh,
    const _Float16* __restrict__ Wh,
    const float* __restrict__ brel, int N)
{
    const int lane = threadIdx.x & 63;
    const int wv   = threadIdx.x >> 6;
    const int l15  = lane & 15;
    const int hi4  = lane >> 4;
    const int tbase = blockIdx.x * 64 + wv * 16;
    const int m0 = min(tbase + l15, N - 1);

    const float* mrow = inout + (size_t)m0 * D;
    const _Float16* xrow = xh + (size_t)m0 * D;

    half8 af[8];
    #pragma unroll
    for (int kb = 0; kb < 4; ++kb) {
        float4 f0 = *reinterpret_cast<const float4*>(mrow + kb * 32 + hi4 * 8);
        float4 f1 = *reinterpret_cast<const float4*>(mrow + kb * 32 + hi4 * 8 + 4);
        half8 a;
        a[0] = (_Float16)f0.x; a[1] = (_Float16)f0.y;
        a[2] = (_Float16)f0.z; a[3] = (_Float16)f0.w;
        a[4] = (_Float16)f1.x; a[5] = (_Float16)f1.y;
        a[6] = (_Float16)f1.z; a[7] = (_Float16)f1.w;
        af[kb] = a;
    }
    #pragma unroll
    for (int kb = 0; kb < 4; ++kb)
        af[4 + kb] = *reinterpret_cast<const half8*>(xrow + kb * 32 + hi4 * 8);

    f32x4 acc[8];
    #pragma unroll
    for (int nt = 0; nt < 8; ++nt) acc[nt] = (f32x4){0.f, 0.f, 0.f, 0.f};

    #pragma unroll
    for (int kb = 0; kb < 8; ++kb) {
        const int krow = kb * 32 + hi4 * 8;
        #pragma unroll
        for (int nt = 0; nt < 8; ++nt) {
            half8 bh = *reinterpret_cast<const half8*>(Wh + (size_t)(nt * 16 + l15) * 256 + krow);
            acc[nt] = __builtin_amdgcn_mfma_f32_16x16x32_f16(af[kb], bh, acc[nt], 0, 0, 0);
        }
    }

    float bias[8];
    #pragma unroll
    for (int nt = 0; nt < 8; ++nt) bias[nt] = brel[nt * 16 + l15];

    #pragma unroll
    for (int r = 0; r < 4; ++r) {
        float ss = 0.f;
        #pragma unroll
        for (int nt = 0; nt < 8; ++nt) {
            float a = acc[nt][r] + bias[nt];
            acc[nt][r] = a;
            ss = fmaf(a, a, ss);
        }
        ss += __shfl_xor(ss, 1, 64);
        ss += __shfl_xor(ss, 2, 64);
        ss += __shfl_xor(ss, 4, 64);
        ss += __shfl_xor(ss, 8, 64);
        float inv = 1.0f / fmaxf(sqrtf(ss), 1e-12f);
        int row = tbase + hi4 * 4 + r;
        if (row < N) {
            float* o = inout + (size_t)row * D + l15;
            #pragma unroll
            for (int nt = 0; nt < 8; ++nt)
                o[nt * 16] = acc[nt][r] * inv;
        }
    }
}

extern "C" void kernel_launch(void* const* d_in, const int* in_sizes, int n_in,
                              void* d_out, int out_size, void* d_ws, size_t ws_size,
                              hipStream_t stream)
{
    const float* x    = (const float*)d_in[0];
    const int*   ei   = (const int*)d_in[2];
    const float* Wrel = (const float*)d_in[3];
    const float* brel = (const float*)d_in[4];
    const float* Wroot= (const float*)d_in[5];
    int N = in_sizes[0] / D;
    int E = in_sizes[2] / 2;
    float* out = (float*)d_out;

    // ws layout: Wh[32768] (_Float16) | xh[N*D] (_Float16) |
    //   gbh[NBMAX] boff[NBMAX] gcur[NBMAX] row_ptr[N+1] | bucketed[E] | perm[E]
    _Float16* Wh = (_Float16*)d_ws;
    _Float16* xh = Wh + 32768;

    sage_wprep_h<<<128, 256, 0, stream>>>(Wrel, Wroot, Wh);
    long long total8 = (long long)N * D / 8;
    sage_xprep_h<<<(int)((total8 + 255) / 256), 256, 0, stream>>>(x, xh, total8);

    int nbuck = (N + (1 << BSH) - 1) >> BSH;
    int* gbh     = (int*)(xh + (size_t)N * D);
    int* boff    = gbh + NBMAX;
    int* gcur    = boff + NBMAX;
    int* row_ptr = gcur + NBMAX;
    unsigned* bucketed = (unsigned*)(row_ptr + N + 1);
    int* perm    = (int*)(bucketed + E);
    size_t need  = (size_t)((char*)(perm + E) - (char*)d_ws);

    if (N <= (1 << 17) && nbuck <= NBMAX && need <= ws_size) {
        hipMemsetAsync(gbh, 0, NBMAX * sizeof(int), stream);
        bucket_hist<<<256, 256, 0, stream>>>(ei + E, gbh, E, nbuck);
        bucket_scan<<<1, NBMAX, 0, stream>>>(gbh, boff, gcur, nbuck);
        bucketize<<<(E + PASSA_TILE - 1) / PASSA_TILE, 256, 0, stream>>>(
            ei, gcur, bucketed, E, nbuck);
        bucket_csr<<<nbuck, 256, 0, stream>>>(
            bucketed, gbh, boff, row_ptr, perm, N, E);
        sage_gather_h<<<(N + 3) / 4, 256, 0, stream>>>(xh, row_ptr, perm, out, N);
    } else {
        // emergency path: old hist/scan/fill CSR
        int* hist    = (int*)(xh + (size_t)N * D);
        int* rp      = hist + N;
        int* cursor  = rp + N + 1;
        int* perm2   = cursor + N;
        hipMemsetAsync(hist, 0, (size_t)N * sizeof(int), stream);
        int eblocks = (E + 255) / 256;
        sage_hist_old<<<eblocks, 256, 0, stream>>>(ei, hist, E);
        sage_scan_old<<<1, 1024, 0, stream>>>(hist, rp, cursor, N);
        sage_fill_old<<<eblocks, 256, 0, stream>>>(ei, cursor, perm2, E);
        sage_gather_h<<<(N + 3) / 4, 256, 0, stream>>>(xh, rp, perm2, out, N);
        row_ptr = rp;
    }

    sage_transform_h<<<(N + 63) / 64, 256, 0, stream>>>(out, xh, Wh, brel, N);
}